// Round 2
// baseline (6076.460 us; speedup 1.0000x reference)
//
#include <hip/hip_runtime.h>

// LIF_13984413516471 — exact fixed-point time-parallel LIF scan.
// B=128, S=128, H=128, K=8. Reference: single scalar accumulator per batch,
// sequential over (i,j,k); per substep: s += x; spike = s > th[k];
// out = spike?s:0; s = spike?0:s. Outputs (B,S,K,H) fp32: outs | spikes.

#define NB 128
#define NS 128
#define NH 128
#define NK 8
#define NT (NS * NH)            // 16384 t-positions per batch
#define NC 128                  // time chunks
#define TC (NT / NC)            // 128 t-steps per chunk
#define OUTN ((size_t)NB * NS * NK * NH)

// ---- ws layout (floats) ----
#define WS_XT    0                         // xT  [NT][NB]
#define WS_SREC  (NT * NB)                 // s_recT [NT][NB]
#define WS_ENT   (2 * NT * NB)             // ent [2][NC][NB]
#define WS_FLAGS (2 * NT * NB + 2 * NC * NB)  // (int) flags[NC], cnt, gen

// Transpose x[b][t] -> xT[t][b] (coalesced both sides via LDS tile).
__global__ void lif_transpose(const float* __restrict__ x, float* __restrict__ xT)
{
    __shared__ float tile[32][33];
    int t0 = blockIdx.x * 32;
    int b0 = blockIdx.y * 32;
    int tx = threadIdx.x;   // 0..31
    int ty = threadIdx.y;   // 0..7
#pragma unroll
    for (int r = 0; r < 32; r += 8)
        tile[ty + r][tx] = x[(size_t)(b0 + ty + r) * NT + t0 + tx];
    __syncthreads();
#pragma unroll
    for (int r = 0; r < 32; r += 8)
        xT[(size_t)(t0 + ty + r) * NB + b0 + tx] = tile[tx][ty + r];
}

__global__ void lif_init(float* __restrict__ ent, int* __restrict__ flags)
{
    int i = blockIdx.x * 256 + threadIdx.x;
    if (i < 2 * NC * NB) ent[i] = 0.0f;
    if (i < NC + 2) flags[i] = 0;
}

// Persistent fixed-point refinement. Block c owns time chunk c; thread = b.
// Each round: run chunk from current entering estimate (recording s_recT),
// publish exit as next chunk's entering, converge when nothing changes
// bitwise. Fixed point == exact sequential result (entering[0]=0 exact;
// exactness propagates >=1 chunk/round; worst case NC rounds).
__global__ void __launch_bounds__(NB, 1)
lif_refine(const float* __restrict__ xT, const float* __restrict__ th,
           float* __restrict__ ent, float* __restrict__ s_recT,
           int* __restrict__ flags)
{
    const int c = blockIdx.x;
    const int b = threadIdx.x;
    int* cnt = flags + NC;
    int* gen = flags + NC + 1;
    __shared__ int sdiff;
    __shared__ int sbrk;

    const float th0 = th[0], th1 = th[1], th2 = th[2], th3 = th[3];
    const float th4 = th[4], th5 = th[5], th6 = th[6], th7 = th[7];
    const int t0 = c * TC;
    int p = 0;

    for (int r = 0; r < NC; ++r) {
        if (threadIdx.x == 0) { sdiff = 0; }
        __syncthreads();

        float s = __hip_atomic_load(&ent[p * NC * NB + c * NB + b],
                                    __ATOMIC_RELAXED, __HIP_MEMORY_SCOPE_AGENT);
        float xv_next = xT[(size_t)t0 * NB + b];
        for (int t = t0; t < t0 + TC; ++t) {
            float xv = xv_next;
            if (t + 1 < t0 + TC) xv_next = xT[(size_t)(t + 1) * NB + b];
            s_recT[(size_t)t * NB + b] = s;   // entering state for this t
            s += xv; s = (s > th0) ? 0.0f : s;
            s += xv; s = (s > th1) ? 0.0f : s;
            s += xv; s = (s > th2) ? 0.0f : s;
            s += xv; s = (s > th3) ? 0.0f : s;
            s += xv; s = (s > th4) ? 0.0f : s;
            s += xv; s = (s > th5) ? 0.0f : s;
            s += xv; s = (s > th6) ? 0.0f : s;
            s += xv; s = (s > th7) ? 0.0f : s;
        }

        if (c + 1 < NC) {
            float prev = __hip_atomic_load(&ent[p * NC * NB + (c + 1) * NB + b],
                                           __ATOMIC_RELAXED, __HIP_MEMORY_SCOPE_AGENT);
            __hip_atomic_store(&ent[(p ^ 1) * NC * NB + (c + 1) * NB + b], s,
                               __ATOMIC_RELAXED, __HIP_MEMORY_SCOPE_AGENT);
            if (__float_as_uint(prev) != __float_as_uint(s)) sdiff = 1;
        }
        __syncthreads();
        if (threadIdx.x == 0 && sdiff) atomicOr(&flags[r], 1);

        // ---- device-scope grid barrier (sense via monotone generation) ----
        __threadfence();
        if (threadIdx.x == 0) {
            int g = __hip_atomic_load(gen, __ATOMIC_ACQUIRE, __HIP_MEMORY_SCOPE_AGENT);
            int a = __hip_atomic_fetch_add(cnt, 1, __ATOMIC_ACQ_REL, __HIP_MEMORY_SCOPE_AGENT);
            if (a == NC - 1) {
                __hip_atomic_store(cnt, 0, __ATOMIC_RELAXED, __HIP_MEMORY_SCOPE_AGENT);
                __hip_atomic_fetch_add(gen, 1, __ATOMIC_ACQ_REL, __HIP_MEMORY_SCOPE_AGENT);
            } else {
                while (__hip_atomic_load(gen, __ATOMIC_ACQUIRE, __HIP_MEMORY_SCOPE_AGENT) == g)
                    __builtin_amdgcn_s_sleep(2);
            }
            __threadfence();
            sbrk = __hip_atomic_load(&flags[r], __ATOMIC_RELAXED, __HIP_MEMORY_SCOPE_AGENT);
        }
        __syncthreads();
        p ^= 1;
        if (sbrk == 0) break;   // converged: this round's s_recT is exact
    }
}

// Output replay, fully parallel. blockIdx = i*NB + b ordering so consecutive
// blocks (same i, neighboring b) share s_recT cache lines. Writes coalesced.
__global__ void lif_out_T(const float* __restrict__ x, const float* __restrict__ th,
                          const float* __restrict__ s_recT, float* __restrict__ out)
{
    int j = threadIdx.x;             // 0..127
    int b = blockIdx.x & (NB - 1);
    int i = blockIdx.x >> 7;
    int t = i * NH + j;

    float s  = s_recT[(size_t)t * NB + b];
    float xv = x[(size_t)b * NT + t];

    float thr[NK];
#pragma unroll
    for (int k = 0; k < NK; ++k) thr[k] = th[k];

    float* o  = out + (((size_t)b * NS + i) * NK) * NH + j;
    float* sp = o + OUTN;

#pragma unroll
    for (int k = 0; k < NK; ++k) {
        s += xv;
        bool spike = s > thr[k];
        o[(size_t)k * NH]  = spike ? s : 0.0f;
        sp[(size_t)k * NH] = spike ? 1.0f : 0.0f;
        s = spike ? 0.0f : s;
    }
}

// ---------------- fallbacks (small ws) ----------------
__global__ void lif_chain(const float* __restrict__ x, const float* __restrict__ th,
                          float* __restrict__ s_rec)
{
    int b = blockIdx.x * 64 + threadIdx.x;
    if (b >= NB) return;
    float th0 = th[0], th1 = th[1], th2 = th[2], th3 = th[3];
    float th4 = th[4], th5 = th[5], th6 = th[6], th7 = th[7];
    const float* xb = x + (size_t)b * NT;
    float* sb = s_rec + (size_t)b * NT;
    float s = 0.0f;
    for (int t = 0; t < NT; ++t) {
        sb[t] = s;
        float xv = xb[t];
        s += xv; s = (s > th0) ? 0.0f : s;
        s += xv; s = (s > th1) ? 0.0f : s;
        s += xv; s = (s > th2) ? 0.0f : s;
        s += xv; s = (s > th3) ? 0.0f : s;
        s += xv; s = (s > th4) ? 0.0f : s;
        s += xv; s = (s > th5) ? 0.0f : s;
        s += xv; s = (s > th6) ? 0.0f : s;
        s += xv; s = (s > th7) ? 0.0f : s;
    }
}

__global__ void lif_out_B(const float* __restrict__ x, const float* __restrict__ th,
                          const float* __restrict__ s_rec, float* __restrict__ out)
{
    int j = threadIdx.x;
    int i = blockIdx.x & (NS - 1);
    int b = blockIdx.x >> 7;
    int t = i * NH + j;
    float s  = s_rec[(size_t)b * NT + t];
    float xv = x[(size_t)b * NT + t];
    float thr[NK];
#pragma unroll
    for (int k = 0; k < NK; ++k) thr[k] = th[k];
    float* o  = out + (((size_t)b * NS + i) * NK) * NH + j;
    float* sp = o + OUTN;
#pragma unroll
    for (int k = 0; k < NK; ++k) {
        s += xv;
        bool spike = s > thr[k];
        o[(size_t)k * NH]  = spike ? s : 0.0f;
        sp[(size_t)k * NH] = spike ? 1.0f : 0.0f;
        s = spike ? 0.0f : s;
    }
}

__global__ void lif_mono(const float* __restrict__ x, const float* __restrict__ th,
                         float* __restrict__ out)
{
    int b = blockIdx.x * 64 + threadIdx.x;
    if (b >= NB) return;
    float thr[NK];
#pragma unroll
    for (int k = 0; k < NK; ++k) thr[k] = th[k];
    const float* xb = x + (size_t)b * NT;
    float s = 0.0f;
    for (int i = 0; i < NS; ++i)
        for (int j = 0; j < NH; ++j) {
            float xv = xb[i * NH + j];
#pragma unroll
            for (int k = 0; k < NK; ++k) {
                s += xv;
                bool spike = s > thr[k];
                size_t idx = (((size_t)b * NS + i) * NK + k) * NH + j;
                out[idx]        = spike ? s : 0.0f;
                out[OUTN + idx] = spike ? 1.0f : 0.0f;
                s = spike ? 0.0f : s;
            }
        }
}

extern "C" void kernel_launch(void* const* d_in, const int* in_sizes, int n_in,
                              void* d_out, int out_size, void* d_ws, size_t ws_size,
                              hipStream_t stream) {
    const float* x  = (const float*)d_in[0];   // (128,128,128) fp32
    const float* th = (const float*)d_in[1];   // (8,) fp32
    float* out = (float*)d_out;

    const size_t need = (size_t)(WS_FLAGS) * 4 + (NC + 2) * 4;
    if (ws_size >= need) {
        float* ws    = (float*)d_ws;
        float* xT    = ws + WS_XT;
        float* sT    = ws + WS_SREC;
        float* ent   = ws + WS_ENT;
        int*   flags = (int*)(ws + WS_FLAGS);

        lif_transpose<<<dim3(NT / 32, NB / 32), dim3(32, 8), 0, stream>>>(x, xT);
        lif_init<<<dim3((2 * NC * NB + 255) / 256), dim3(256), 0, stream>>>(ent, flags);
        lif_refine<<<dim3(NC), dim3(NB), 0, stream>>>(xT, th, ent, sT, flags);
        lif_out_T<<<dim3(NB * NS), dim3(NH), 0, stream>>>(x, th, sT, out);
    } else if (ws_size >= (size_t)NB * NT * 4) {
        float* s_rec = (float*)d_ws;
        lif_chain<<<dim3(2), dim3(64), 0, stream>>>(x, th, s_rec);
        lif_out_B<<<dim3(NB * NS), dim3(NH), 0, stream>>>(x, th, s_rec, out);
    } else {
        lif_mono<<<dim3(2), dim3(64), 0, stream>>>(x, th, out);
    }
}

// Round 3
// 1475.446 us; speedup vs baseline: 4.1184x; 4.1184x over previous
//
#include <hip/hip_runtime.h>

// LIF_13984413516471 — exact serial chain with certified quiet-window fast path.
// B=128, S=128, H=128, K=8. Reference: single scalar accumulator per batch,
// sequential over (i,j,k); per substep: s += x; if (s > th[k]) s = 0.
// Outputs (B,S,K,H) fp32: outs | spikes. Must be bitwise-exact fp32 replay.

#define NB 128
#define NS 128
#define NH 128
#define NK 8
#define NT (NS * NH)            // 16384 t-positions per batch
#define WLEN 16                 // window = 16 t-steps
#define NW (NT / WLEN)          // 1024 windows
#define OUTN ((size_t)NB * NS * NK * NH)

// ---- ws layout (floats) ----
#define WS_XT    0                          // xT   [NT][NB]
#define WS_CB    (NT * NB)                  // CB   [NW][NB]
#define WS_SENT  (NT * NB + NW * NB)        // s_ent[NS][NB]
#define WS_TOTAL (NT * NB + NW * NB + NS * NB)

// Transpose x[b][t] -> xT[t][b] (coalesced both sides via LDS tile).
__global__ void lif_transpose(const float* __restrict__ x, float* __restrict__ xT)
{
    __shared__ float tile[32][33];
    int t0 = blockIdx.x * 32;
    int b0 = blockIdx.y * 32;
    int tx = threadIdx.x;   // 0..31
    int ty = threadIdx.y;   // 0..7
#pragma unroll
    for (int r = 0; r < 32; r += 8)
        tile[ty + r][tx] = x[(size_t)(b0 + ty + r) * NT + t0 + tx];
    __syncthreads();
#pragma unroll
    for (int r = 0; r < 32; r += 8)
        xT[(size_t)(t0 + ty + r) * NB + b0 + tx] = tile[tx][ty + r];
}

// Per-(b,window) conservative upper bound on the max prefix climb of the
// no-reset substep sums, computed in f64 from 0. Any real-arith prefix value
// within the window is <= C; margin covers f64->f32 and fp32 chain drift.
__global__ void lif_bounds(const float* __restrict__ xT, float* __restrict__ CB)
{
    int b = threadIdx.x;        // 0..127
    int w = blockIdx.x;         // 0..NW-1
    double p = 0.0, maxp = -1e300;
#pragma unroll 4
    for (int l = 0; l < WLEN; ++l) {
        double xv = (double)xT[(size_t)(w * WLEN + l) * NB + b];
#pragma unroll
        for (int k = 0; k < NK; ++k) { p += xv; maxp = fmax(maxp, p); }
    }
    CB[(size_t)w * NB + b] = (float)(maxp + 1e-3 + 1e-6 * fabs(maxp));
}

// The serial chain. One lane per batch, 2 blocks x 64 (one wave each).
// Coalesced xT loads, double-buffered one window ahead. Stores entering
// state at each i boundary only. Quiet windows (certified, wave-uniform)
// take the pure-add path: bitwise identical, 3x shorter dep chain.
__global__ void __launch_bounds__(64, 1)
lif_chain_T(const float* __restrict__ xT, const float* __restrict__ th,
            const float* __restrict__ CB, float* __restrict__ s_ent)
{
    int b = blockIdx.x * 64 + threadIdx.x;
    const float th0 = th[0], th1 = th[1], th2 = th[2], th3 = th[3];
    const float th4 = th[4], th5 = th[5], th6 = th[6], th7 = th[7];
    const float minth = fminf(fminf(fminf(th0, th1), fminf(th2, th3)),
                              fminf(fminf(th4, th5), fminf(th6, th7)));
    float s = 0.0f;
    float xa[WLEN], xb[WLEN];
#pragma unroll
    for (int l = 0; l < WLEN; ++l) xa[l] = xT[(size_t)l * NB + b];

    for (int w = 0; w < NW; ++w) {
        if (w + 1 < NW) {
#pragma unroll
            for (int l = 0; l < WLEN; ++l)
                xb[l] = xT[(size_t)((w + 1) * WLEN + l) * NB + b];
        }
        if ((w & 7) == 0) s_ent[(w >> 3) * NB + b] = s;  // i = w/8 entering state

        float C = CB[(size_t)w * NB + b];
        bool quiet = (s + C + 1.6e-5f * (fabsf(s) + fabsf(C)) + 1e-3f < minth);
        if (__all(quiet)) {
            // certified: no lane spikes anywhere in this window
#pragma unroll
            for (int l = 0; l < WLEN; ++l) {
                float xv = xa[l];
                s += xv; s += xv; s += xv; s += xv;
                s += xv; s += xv; s += xv; s += xv;
            }
        } else {
#pragma unroll
            for (int l = 0; l < WLEN; ++l) {
                float xv = xa[l];
                s += xv; if (s > th0) s = 0.0f;
                s += xv; if (s > th1) s = 0.0f;
                s += xv; if (s > th2) s = 0.0f;
                s += xv; if (s > th3) s = 0.0f;
                s += xv; if (s > th4) s = 0.0f;
                s += xv; if (s > th5) s = 0.0f;
                s += xv; if (s > th6) s = 0.0f;
                s += xv; if (s > th7) s = 0.0f;
            }
        }
#pragma unroll
        for (int l = 0; l < WLEN; ++l) xa[l] = xb[l];
    }
}

// Output pass: block = (b, i). Thread 0 replays the 128-j row serially from
// s_ent (recording entering states in LDS), then all 128 threads emit the
// 8 outputs for their j, coalesced per k-plane. Bitwise-exact replay.
__global__ void __launch_bounds__(128)
lif_out_chunk(const float* __restrict__ x, const float* __restrict__ th,
              const float* __restrict__ s_ent, float* __restrict__ out)
{
    __shared__ float xs[NH];
    __shared__ float srow[NH];
    int j = threadIdx.x;             // 0..127
    int i = blockIdx.x & (NS - 1);
    int b = blockIdx.x >> 7;

    xs[j] = x[(size_t)b * NT + i * NH + j];
    __syncthreads();

    if (j == 0) {
        const float t0 = th[0], t1 = th[1], t2 = th[2], t3 = th[3];
        const float t4 = th[4], t5 = th[5], t6 = th[6], t7 = th[7];
        float s = s_ent[i * NB + b];
        for (int jj = 0; jj < NH; ++jj) {
            srow[jj] = s;
            float xv = xs[jj];
            s += xv; if (s > t0) s = 0.0f;
            s += xv; if (s > t1) s = 0.0f;
            s += xv; if (s > t2) s = 0.0f;
            s += xv; if (s > t3) s = 0.0f;
            s += xv; if (s > t4) s = 0.0f;
            s += xv; if (s > t5) s = 0.0f;
            s += xv; if (s > t6) s = 0.0f;
            s += xv; if (s > t7) s = 0.0f;
        }
    }
    __syncthreads();

    float s  = srow[j];
    float xv = xs[j];
    float thr[NK];
#pragma unroll
    for (int k = 0; k < NK; ++k) thr[k] = th[k];

    float* o  = out + (((size_t)b * NS + i) * NK) * NH + j;
    float* sp = o + OUTN;
#pragma unroll
    for (int k = 0; k < NK; ++k) {
        s += xv;
        bool spike = s > thr[k];
        o[(size_t)k * NH]  = spike ? s : 0.0f;
        sp[(size_t)k * NH] = spike ? 1.0f : 0.0f;
        s = spike ? 0.0f : s;
    }
}

// Fallback if ws is too small: single-pass, scattered writes (slow, correct).
__global__ void lif_mono(const float* __restrict__ x, const float* __restrict__ th,
                         float* __restrict__ out)
{
    int b = blockIdx.x * 64 + threadIdx.x;
    if (b >= NB) return;
    float thr[NK];
#pragma unroll
    for (int k = 0; k < NK; ++k) thr[k] = th[k];
    const float* xb = x + (size_t)b * NT;
    float s = 0.0f;
    for (int i = 0; i < NS; ++i)
        for (int j = 0; j < NH; ++j) {
            float xv = xb[i * NH + j];
#pragma unroll
            for (int k = 0; k < NK; ++k) {
                s += xv;
                bool spike = s > thr[k];
                size_t idx = (((size_t)b * NS + i) * NK + k) * NH + j;
                out[idx]        = spike ? s : 0.0f;
                out[OUTN + idx] = spike ? 1.0f : 0.0f;
                s = spike ? 0.0f : s;
            }
        }
}

extern "C" void kernel_launch(void* const* d_in, const int* in_sizes, int n_in,
                              void* d_out, int out_size, void* d_ws, size_t ws_size,
                              hipStream_t stream) {
    const float* x  = (const float*)d_in[0];   // (128,128,128) fp32
    const float* th = (const float*)d_in[1];   // (8,) fp32
    float* out = (float*)d_out;

    if (ws_size >= (size_t)WS_TOTAL * sizeof(float)) {
        float* ws    = (float*)d_ws;
        float* xT    = ws + WS_XT;
        float* CB    = ws + WS_CB;
        float* s_ent = ws + WS_SENT;

        lif_transpose<<<dim3(NT / 32, NB / 32), dim3(32, 8), 0, stream>>>(x, xT);
        lif_bounds<<<dim3(NW), dim3(NB), 0, stream>>>(xT, CB);
        lif_chain_T<<<dim3(2), dim3(64), 0, stream>>>(xT, th, CB, s_ent);
        lif_out_chunk<<<dim3(NB * NS), dim3(NH), 0, stream>>>(x, th, s_ent, out);
    } else {
        lif_mono<<<dim3(2), dim3(64), 0, stream>>>(x, th, out);
    }
}

// Round 4
// 920.764 us; speedup vs baseline: 6.5994x; 1.6024x over previous
//
#include <hip/hip_runtime.h>
#include <math.h>

// LIF_13984413516471 — exact serial chain, 1 batch per wave, certified
// per-t quiet fast path. B=128, S=128, H=128, K=8.
// Reference: single scalar accumulator per batch, sequential over (i,j,k);
// per substep: s += x; if (s > th[k]) s = 0.
// Outputs (B,S,K,H) fp32: outs | spikes. Bitwise-exact fp32 replay.

#define NB 128
#define NS 128
#define NH 128
#define NK 8
#define NT (NS * NH)            // 16384 t-positions per batch
#define OUTN ((size_t)NB * NS * NK * NH)

// ---- ws layout (floats) ----
#define WS_MB    0                      // m_hat [NB][NT]
#define WS_SREC  (NB * NT)              // s_rec [NB][NT]
#define WS_TOTAL (2 * NB * NT)

// Per-(b,t) conservative quiet boundary: m_hat = minth - C - margin, where
// C (f64) >= max prefix climb of the 8 same-x substeps. If entering s <=
// m_hat, the fp32 chain provably never exceeds any threshold in this t
// (margin 0.01 covers 8-add fp32 drift at |s|<=4200, which is <=0.004).
__global__ void lif_bounds(const float* __restrict__ x,
                           const float* __restrict__ th,
                           float* __restrict__ mhat)
{
    int idx = blockIdx.x * 256 + threadIdx.x;   // flat over NB*NT
    if (idx >= NB * NT) return;
    float minth = th[0];
#pragma unroll
    for (int k = 1; k < NK; ++k) minth = fminf(minth, th[k]);
    double xv = (double)x[idx];
    double p = 0.0, maxp = -1e300;
#pragma unroll
    for (int k = 0; k < NK; ++k) { p += xv; maxp = fmax(maxp, p); }
    double m = (double)minth - maxp - 0.01 - 1e-6 * fabs(maxp);
    mhat[idx] = (float)m;
}

// Serial chain: one batch per wave (block). Lane 0 carries the scalar state;
// the fast/slow branch is wave-uniform by construction. Streams x, mhat
// contiguously with an 8-deep register double buffer; stores entering state
// per t (contiguous). Fast path (certified no-spike): 8 pure adds — bitwise
// identical to the reference chain. Slow path: exact substeps.
__global__ void __launch_bounds__(64, 1)
lif_chain(const float* __restrict__ x, const float* __restrict__ th,
          const float* __restrict__ mhat, float* __restrict__ s_rec)
{
    if (threadIdx.x != 0) return;
    int b = blockIdx.x;
    const float* xb = x + (size_t)b * NT;
    const float* mb = mhat + (size_t)b * NT;
    float* sb = s_rec + (size_t)b * NT;

    const float th0 = th[0], th1 = th[1], th2 = th[2], th3 = th[3];
    const float th4 = th[4], th5 = th[5], th6 = th[6], th7 = th[7];

    float s = 0.0f;
    float xw[8], mw[8], xn[8], mn[8];
#pragma unroll
    for (int l = 0; l < 8; ++l) { xw[l] = xb[l]; mw[l] = mb[l]; }

    for (int w = 0; w < NT / 8; ++w) {
        const int tb = w * 8;
        if (w + 1 < NT / 8) {
#pragma unroll
            for (int l = 0; l < 8; ++l) {
                xn[l] = xb[tb + 8 + l];
                mn[l] = mb[tb + 8 + l];
            }
        }
#pragma unroll
        for (int l = 0; l < 8; ++l) {
            sb[tb + l] = s;
            float xv = xw[l];
            if (s <= mw[l]) {
                // certified: no spike anywhere in this t-step
                s += xv; s += xv; s += xv; s += xv;
                s += xv; s += xv; s += xv; s += xv;
            } else {
                s += xv; if (s > th0) s = 0.0f;
                s += xv; if (s > th1) s = 0.0f;
                s += xv; if (s > th2) s = 0.0f;
                s += xv; if (s > th3) s = 0.0f;
                s += xv; if (s > th4) s = 0.0f;
                s += xv; if (s > th5) s = 0.0f;
                s += xv; if (s > th6) s = 0.0f;
                s += xv; if (s > th7) s = 0.0f;
            }
        }
#pragma unroll
        for (int l = 0; l < 8; ++l) { xw[l] = xn[l]; mw[l] = mn[l]; }
    }
}

// Output pass: fully parallel. block = (b, i), thread = j.
// Reads s_rec[b][i*NH+j] and x[b][i*NH+j] coalesced; replays the 8 substeps
// bitwise-exactly; writes outs/spikes coalesced per k-plane.
__global__ void __launch_bounds__(128)
lif_out(const float* __restrict__ x, const float* __restrict__ th,
        const float* __restrict__ s_rec, float* __restrict__ out)
{
    int j = threadIdx.x;             // 0..127
    int i = blockIdx.x & (NS - 1);
    int b = blockIdx.x >> 7;
    int t = i * NH + j;

    float s  = s_rec[(size_t)b * NT + t];
    float xv = x[(size_t)b * NT + t];

    float thr[NK];
#pragma unroll
    for (int k = 0; k < NK; ++k) thr[k] = th[k];

    float* o  = out + (((size_t)b * NS + i) * NK) * NH + j;
    float* sp = o + OUTN;
#pragma unroll
    for (int k = 0; k < NK; ++k) {
        s += xv;
        bool spike = s > thr[k];
        o[(size_t)k * NH]  = spike ? s : 0.0f;
        sp[(size_t)k * NH] = spike ? 1.0f : 0.0f;
        s = spike ? 0.0f : s;
    }
}

// Fallback if ws is too small: single-pass, scattered writes (slow, correct).
__global__ void lif_mono(const float* __restrict__ x, const float* __restrict__ th,
                         float* __restrict__ out)
{
    int b = blockIdx.x * 64 + threadIdx.x;
    if (b >= NB) return;
    float thr[NK];
#pragma unroll
    for (int k = 0; k < NK; ++k) thr[k] = th[k];
    const float* xb = x + (size_t)b * NT;
    float s = 0.0f;
    for (int i = 0; i < NS; ++i)
        for (int j = 0; j < NH; ++j) {
            float xv = xb[i * NH + j];
#pragma unroll
            for (int k = 0; k < NK; ++k) {
                s += xv;
                bool spike = s > thr[k];
                size_t idx = (((size_t)b * NS + i) * NK + k) * NH + j;
                out[idx]        = spike ? s : 0.0f;
                out[OUTN + idx] = spike ? 1.0f : 0.0f;
                s = spike ? 0.0f : s;
            }
        }
}

extern "C" void kernel_launch(void* const* d_in, const int* in_sizes, int n_in,
                              void* d_out, int out_size, void* d_ws, size_t ws_size,
                              hipStream_t stream) {
    const float* x  = (const float*)d_in[0];   // (128,128,128) fp32
    const float* th = (const float*)d_in[1];   // (8,) fp32
    float* out = (float*)d_out;

    if (ws_size >= (size_t)WS_TOTAL * sizeof(float)) {
        float* ws    = (float*)d_ws;
        float* mhat  = ws + WS_MB;
        float* s_rec = ws + WS_SREC;

        lif_bounds<<<dim3((NB * NT + 255) / 256), dim3(256), 0, stream>>>(x, th, mhat);
        lif_chain<<<dim3(NB), dim3(64), 0, stream>>>(x, th, mhat, s_rec);
        lif_out<<<dim3(NB * NS), dim3(128), 0, stream>>>(x, th, s_rec, out);
    } else {
        lif_mono<<<dim3(2), dim3(64), 0, stream>>>(x, th, out);
    }
}

// Round 5
// 753.776 us; speedup vs baseline: 8.0614x; 1.2215x over previous
//
#include <hip/hip_runtime.h>
#include <math.h>

// LIF_13984413516471 — exact serial chain, 1 batch per wave, window-level
// certified quiet fast path with a FORCED scalar branch (readfirstlane).
// B=128, S=128, H=128, K=8. Reference: one scalar accumulator per batch,
// sequential over (i,j,k); per substep: s += x; if (s > th[k]) s = 0.
// Outputs (B,S,K,H) fp32: outs | spikes. Bitwise-exact fp32 replay.

#define NB 128
#define NS 128
#define NH 128
#define NK 8
#define NT (NS * NH)            // 16384 t-positions per batch
#define WL 8                    // window = 8 t-steps (64 substeps)
#define NW2 (NT / WL)           // 2048 windows per batch
#define OUTN ((size_t)NB * NS * NK * NH)

// ---- ws layout (floats) ----
#define WS_M     0                      // M    [NB][NW2]
#define WS_SREC  (NB * NW2)             // s_rec[NB][NT]
#define WS_TOTAL (NB * NW2 + NB * NT)

// Per-(b,window) quiet bound, f64: M = minth - maxPrefix - margin where
// maxPrefix >= max prefix sum of the 64 substep adds from window entry.
// If entering s <= M, the real-arith chain stays >= margin below minth all
// window; fp32 drift over 64 adds at |s|<=26000 is < 0.1 = margin, so the
// fp32 chain provably never spikes -> pure adds are bitwise-exact.
__global__ void lif_bounds8(const float* __restrict__ x,
                            const float* __restrict__ th,
                            float* __restrict__ M)
{
    int idx = blockIdx.x * 256 + threadIdx.x;   // flat over NB*NW2
    if (idx >= NB * NW2) return;
    float minth = th[0];
#pragma unroll
    for (int k = 1; k < NK; ++k) minth = fminf(minth, th[k]);
    const float* xp = x + (size_t)idx * WL;     // idx = b*NW2 + w -> x[b][w*8]
    double p = 0.0, maxp = -1e300;
#pragma unroll
    for (int l = 0; l < WL; ++l) {
        double xv = (double)xp[l];
#pragma unroll
        for (int k = 0; k < NK; ++k) { p += xv; maxp = fmax(maxp, p); }
    }
    M[idx] = (float)((double)minth - maxp - 0.1 - 1e-6 * fabs(maxp));
}

#define ADD8(xv) do { s += xv; s += xv; s += xv; s += xv; \
                      s += xv; s += xv; s += xv; s += xv; } while (0)
#define STEP8(xv) do { \
    s += xv; s = (s > th0) ? 0.0f : s; \
    s += xv; s = (s > th1) ? 0.0f : s; \
    s += xv; s = (s > th2) ? 0.0f : s; \
    s += xv; s = (s > th3) ? 0.0f : s; \
    s += xv; s = (s > th4) ? 0.0f : s; \
    s += xv; s = (s > th5) ? 0.0f : s; \
    s += xv; s = (s > th6) ? 0.0f : s; \
    s += xv; s = (s > th7) ? 0.0f : s; } while (0)

// Serial chain: one batch per wave. Lane 0 carries the state. Window-level
// vote via readfirstlane -> SGPR -> s_cbranch (cannot be if-converted).
// Fast window: 64 pure dependent adds. Slow window: 64 exact substeps.
// Stores entering state per t as two float4 per window.
__global__ void __launch_bounds__(64, 1)
lif_chain(const float* __restrict__ x, const float* __restrict__ th,
          const float* __restrict__ M, float* __restrict__ s_rec)
{
    if (threadIdx.x != 0) return;
    int b = blockIdx.x;
    const float4* xb = (const float4*)(x + (size_t)b * NT);
    const float*  Mb = M + (size_t)b * NW2;
    float*        sb = s_rec + (size_t)b * NT;

    const float th0 = th[0], th1 = th[1], th2 = th[2], th3 = th[3];
    const float th4 = th[4], th5 = th[5], th6 = th[6], th7 = th[7];

    float s = 0.0f;
    float4 cx0 = xb[0], cx1 = xb[1];
    float  cM  = Mb[0];
    float4 nx0 = cx0, nx1 = cx1;
    float  nM  = cM;

    for (int w = 0; w < NW2; ++w) {
        if (w + 1 < NW2) {
            nx0 = xb[(size_t)(w + 1) * 2];
            nx1 = xb[(size_t)(w + 1) * 2 + 1];
            nM  = Mb[w + 1];
        }
        float4 r0, r1;   // entering states for t = w*8 .. w*8+7
        int q = __builtin_amdgcn_readfirstlane((int)(s <= cM));
        if (q) {
            // certified spike-free window: pure adds (bitwise identical)
            r0.x = s; ADD8(cx0.x);
            r0.y = s; ADD8(cx0.y);
            r0.z = s; ADD8(cx0.z);
            r0.w = s; ADD8(cx0.w);
            r1.x = s; ADD8(cx1.x);
            r1.y = s; ADD8(cx1.y);
            r1.z = s; ADD8(cx1.z);
            r1.w = s; ADD8(cx1.w);
        } else {
            r0.x = s; STEP8(cx0.x);
            r0.y = s; STEP8(cx0.y);
            r0.z = s; STEP8(cx0.z);
            r0.w = s; STEP8(cx0.w);
            r1.x = s; STEP8(cx1.x);
            r1.y = s; STEP8(cx1.y);
            r1.z = s; STEP8(cx1.z);
            r1.w = s; STEP8(cx1.w);
        }
        float4* srp = (float4*)(sb + (size_t)w * WL);
        srp[0] = r0;
        srp[1] = r1;
        cx0 = nx0; cx1 = nx1; cM = nM;
    }
}

// Output pass: fully parallel. block = (b, i), thread = j.
// Reads s_rec[b][i*NH+j] and x[b][i*NH+j] coalesced; replays the 8 substeps
// bitwise-exactly; writes outs/spikes coalesced per k-plane.
__global__ void __launch_bounds__(128)
lif_out(const float* __restrict__ x, const float* __restrict__ th,
        const float* __restrict__ s_rec, float* __restrict__ out)
{
    int j = threadIdx.x;             // 0..127
    int i = blockIdx.x & (NS - 1);
    int b = blockIdx.x >> 7;
    int t = i * NH + j;

    float s  = s_rec[(size_t)b * NT + t];
    float xv = x[(size_t)b * NT + t];

    float thr[NK];
#pragma unroll
    for (int k = 0; k < NK; ++k) thr[k] = th[k];

    float* o  = out + (((size_t)b * NS + i) * NK) * NH + j;
    float* sp = o + OUTN;
#pragma unroll
    for (int k = 0; k < NK; ++k) {
        s += xv;
        bool spike = s > thr[k];
        o[(size_t)k * NH]  = spike ? s : 0.0f;
        sp[(size_t)k * NH] = spike ? 1.0f : 0.0f;
        s = spike ? 0.0f : s;
    }
}

// Fallback if ws is too small: single-pass, scattered writes (slow, correct).
__global__ void lif_mono(const float* __restrict__ x, const float* __restrict__ th,
                         float* __restrict__ out)
{
    int b = blockIdx.x * 64 + threadIdx.x;
    if (b >= NB) return;
    float thr[NK];
#pragma unroll
    for (int k = 0; k < NK; ++k) thr[k] = th[k];
    const float* xb = x + (size_t)b * NT;
    float s = 0.0f;
    for (int i = 0; i < NS; ++i)
        for (int j = 0; j < NH; ++j) {
            float xv = xb[i * NH + j];
#pragma unroll
            for (int k = 0; k < NK; ++k) {
                s += xv;
                bool spike = s > thr[k];
                size_t idx = (((size_t)b * NS + i) * NK + k) * NH + j;
                out[idx]        = spike ? s : 0.0f;
                out[OUTN + idx] = spike ? 1.0f : 0.0f;
                s = spike ? 0.0f : s;
            }
        }
}

extern "C" void kernel_launch(void* const* d_in, const int* in_sizes, int n_in,
                              void* d_out, int out_size, void* d_ws, size_t ws_size,
                              hipStream_t stream) {
    const float* x  = (const float*)d_in[0];   // (128,128,128) fp32
    const float* th = (const float*)d_in[1];   // (8,) fp32
    float* out = (float*)d_out;

    if (ws_size >= (size_t)WS_TOTAL * sizeof(float)) {
        float* ws    = (float*)d_ws;
        float* Mbuf  = ws + WS_M;
        float* s_rec = ws + WS_SREC;

        lif_bounds8<<<dim3((NB * NW2 + 255) / 256), dim3(256), 0, stream>>>(x, th, Mbuf);
        lif_chain<<<dim3(NB), dim3(64), 0, stream>>>(x, th, Mbuf, s_rec);
        lif_out<<<dim3(NB * NS), dim3(128), 0, stream>>>(x, th, s_rec, out);
    } else {
        lif_mono<<<dim3(2), dim3(64), 0, stream>>>(x, th, out);
    }
}